// Round 5
// baseline (1697.930 us; speedup 1.0000x reference)
//
#include <hip/hip_runtime.h>
#include <hip/hip_bf16.h>

#define NSEQ 2048
#define DIMM 1024
#define NHEADS 16
#define DHEAD 64

typedef __attribute__((ext_vector_type(8))) short bf16x8;
typedef __attribute__((ext_vector_type(4))) float f32x4;

__device__ inline unsigned short f2bfu(float f) {
  unsigned int x = __float_as_uint(f);
  unsigned int r = (x + 0x7fffu + ((x >> 16) & 1u)) >> 16;
  return (unsigned short)r;
}

// ---------------- transpose + cast f32 -> bf16 ----------------
// out[n][k] = in[k][c0+n]
__global__ __launch_bounds__(256) void k_tcast(const float* __restrict__ in, int inStride, int c0,
                                               unsigned short* __restrict__ out, int outStride) {
  __shared__ float tile[32][33];
  int n0 = blockIdx.x * 32, k0 = blockIdx.y * 32;
  int tx = threadIdx.x & 31, ty = threadIdx.x >> 5;
  for (int r = ty; r < 32; r += 8)
    tile[r][tx] = in[(size_t)(k0 + r) * inStride + c0 + n0 + tx];
  __syncthreads();
  for (int r = ty; r < 32; r += 8)
    out[(size_t)(n0 + r) * outStride + k0 + tx] = f2bfu(tile[tx][r]);
}

// ---------------- layernorm -> bf16 ----------------
__global__ __launch_bounds__(256) void k_layernorm(const float* __restrict__ x,
    const float* __restrict__ g, const float* __restrict__ b,
    unsigned short* __restrict__ xnb) {
  int row = blockIdx.x;
  int t = threadIdx.x;
  const float4* x4 = reinterpret_cast<const float4*>(x + (size_t)row * DIMM);
  float4 v = x4[t];
  float s = v.x + v.y + v.z + v.w;
  float ss = v.x*v.x + v.y*v.y + v.z*v.z + v.w*v.w;
  for (int off = 32; off; off >>= 1) { s += __shfl_down(s, off); ss += __shfl_down(ss, off); }
  __shared__ float red[4][2];
  int wid = t >> 6, lane = t & 63;
  if (lane == 0) { red[wid][0] = s; red[wid][1] = ss; }
  __syncthreads();
  if (t == 0) {
    float S = 0.f, SS = 0.f;
    for (int w = 0; w < 4; w++) { S += red[w][0]; SS += red[w][1]; }
    float mu = S / DIMM;
    float var = SS / DIMM - mu * mu;
    red[0][0] = mu; red[0][1] = rsqrtf(var + 1e-5f);
  }
  __syncthreads();
  float mu = red[0][0], rstd = red[0][1];
  float4 g4 = reinterpret_cast<const float4*>(g)[t];
  float4 b4 = reinterpret_cast<const float4*>(b)[t];
  ushort4 pk;
  pk.x = f2bfu((v.x - mu) * rstd * g4.x + b4.x);
  pk.y = f2bfu((v.y - mu) * rstd * g4.y + b4.y);
  pk.z = f2bfu((v.z - mu) * rstd * g4.z + b4.z);
  pk.w = f2bfu((v.w - mu) * rstd * g4.w + b4.w);
  *reinterpret_cast<ushort4*>(xnb + (size_t)row * DIMM + t * 4) = pk;
}

// ---------------- generic bf16 MFMA GEMM: C = A(MxK) * Bt(NxK)^T ----------------
// EPI 0: QKV split epilogue (bf16 q,k row-major; v transposed)
// EPI 1: f32 + bias -> oF
template<int EPI>
__global__ __launch_bounds__(256) void k_gemm(
    const unsigned short* __restrict__ A, const unsigned short* __restrict__ Bt,
    int K,
    unsigned short* __restrict__ oQ, unsigned short* __restrict__ oK, unsigned short* __restrict__ oV,
    float* __restrict__ oF, const float* __restrict__ bias) {
  __shared__ unsigned short As[128][40];
  __shared__ unsigned short Bs[128][40];
  int t = threadIdx.x;
  int i0 = blockIdx.y * 128, n0 = blockIdx.x * 128;
  int wid = t >> 6, lane = t & 63;
  int wr = wid >> 1, wc = wid & 1;
  f32x4 acc[4][4];
  #pragma unroll
  for (int a = 0; a < 4; a++)
    #pragma unroll
    for (int b = 0; b < 4; b++)
      #pragma unroll
      for (int e = 0; e < 4; e++) acc[a][b][e] = 0.f;

  const int arow = t >> 1, aoff = (t & 1) * 16;
  for (int k0 = 0; k0 < K; k0 += 32) {
    __syncthreads();
    {
      const int4* sa = reinterpret_cast<const int4*>(A + (size_t)(i0 + arow) * K + k0 + aoff);
      int4 a0 = sa[0], a1 = sa[1];
      const int4* sb = reinterpret_cast<const int4*>(Bt + (size_t)(n0 + arow) * K + k0 + aoff);
      int4 b0 = sb[0], b1 = sb[1];
      *reinterpret_cast<int4*>(&As[arow][aoff]) = a0;
      *reinterpret_cast<int4*>(&As[arow][aoff + 8]) = a1;
      *reinterpret_cast<int4*>(&Bs[arow][aoff]) = b0;
      *reinterpret_cast<int4*>(&Bs[arow][aoff + 8]) = b1;
    }
    __syncthreads();
    bf16x8 af[4], bfr[4];
    #pragma unroll
    for (int fi = 0; fi < 4; fi++)
      af[fi] = *reinterpret_cast<const bf16x8*>(&As[wr * 64 + fi * 16 + (lane & 15)][(lane >> 4) * 8]);
    #pragma unroll
    for (int fj = 0; fj < 4; fj++)
      bfr[fj] = *reinterpret_cast<const bf16x8*>(&Bs[wc * 64 + fj * 16 + (lane & 15)][(lane >> 4) * 8]);
    #pragma unroll
    for (int fi = 0; fi < 4; fi++)
      #pragma unroll
      for (int fj = 0; fj < 4; fj++)
        acc[fi][fj] = __builtin_amdgcn_mfma_f32_16x16x32_bf16(af[fi], bfr[fj], acc[fi][fj], 0, 0, 0);
  }

  int r0 = i0 + wr * 64, c0 = n0 + wc * 64;
  #pragma unroll
  for (int fi = 0; fi < 4; fi++) {
    #pragma unroll
    for (int fj = 0; fj < 4; fj++) {
      int col = c0 + fj * 16 + (lane & 15);
      int rowb = r0 + fi * 16 + ((lane >> 4) << 2);
      if (EPI == 0) {
        if (col < 1024) {
          #pragma unroll
          for (int j = 0; j < 4; j++)
            oQ[(size_t)(rowb + j) * 1024 + col] = f2bfu(acc[fi][fj][j]);
        } else if (col < 2048) {
          #pragma unroll
          for (int j = 0; j < 4; j++)
            oK[(size_t)(rowb + j) * 1024 + col - 1024] = f2bfu(acc[fi][fj][j]);
        } else {
          ushort4 pk;
          pk.x = f2bfu(acc[fi][fj][0]); pk.y = f2bfu(acc[fi][fj][1]);
          pk.z = f2bfu(acc[fi][fj][2]); pk.w = f2bfu(acc[fi][fj][3]);
          *reinterpret_cast<ushort4*>(&oV[(size_t)(col - 2048) * NSEQ + rowb]) = pk;
        }
      } else {
        float bb = bias[col];
        #pragma unroll
        for (int j = 0; j < 4; j++)
          oF[(size_t)(rowb + j) * 1024 + col] = acc[fi][fj][j] + bb;
      }
    }
  }
}

// ---------------- per-head QK^T + blend epilogue ----------------
__global__ __launch_bounds__(256) void k_blend(
    const unsigned short* __restrict__ qb, const unsigned short* __restrict__ kb,
    const float* __restrict__ hbuf, float* __restrict__ blended) {
  __shared__ __align__(16) char smem[67584];
  unsigned short (*As)[72] = reinterpret_cast<unsigned short(*)[72]>(smem);
  unsigned short (*Bs)[72] = reinterpret_cast<unsigned short(*)[72]>(smem + 128 * 72 * 2);
  float (*Cs)[132] = reinterpret_cast<float(*)[132]>(smem);

  int head = blockIdx.z;
  int i0 = blockIdx.y * 128, j0 = blockIdx.x * 128;
  int t = threadIdx.x, wid = t >> 6, lane = t & 63;
  int wr = wid >> 1, wc = wid & 1;

  const int arow = t >> 1, aoff = (t & 1) * 32;
  {
    const int4* sa = reinterpret_cast<const int4*>(qb + (size_t)(i0 + arow) * DIMM + head * 64 + aoff);
    const int4* sb = reinterpret_cast<const int4*>(kb + (size_t)(j0 + arow) * DIMM + head * 64 + aoff);
    int4 a0 = sa[0], a1 = sa[1], a2 = sa[2], a3 = sa[3];
    int4 b0 = sb[0], b1 = sb[1], b2 = sb[2], b3 = sb[3];
    *reinterpret_cast<int4*>(&As[arow][aoff])      = a0;
    *reinterpret_cast<int4*>(&As[arow][aoff + 8])  = a1;
    *reinterpret_cast<int4*>(&As[arow][aoff + 16]) = a2;
    *reinterpret_cast<int4*>(&As[arow][aoff + 24]) = a3;
    *reinterpret_cast<int4*>(&Bs[arow][aoff])      = b0;
    *reinterpret_cast<int4*>(&Bs[arow][aoff + 8])  = b1;
    *reinterpret_cast<int4*>(&Bs[arow][aoff + 16]) = b2;
    *reinterpret_cast<int4*>(&Bs[arow][aoff + 24]) = b3;
  }
  __syncthreads();

  f32x4 acc[4][4];
  #pragma unroll
  for (int a = 0; a < 4; a++)
    #pragma unroll
    for (int b = 0; b < 4; b++)
      #pragma unroll
      for (int e = 0; e < 4; e++) acc[a][b][e] = 0.f;

  #pragma unroll
  for (int kk = 0; kk < 2; kk++) {
    bf16x8 af[4], bfr[4];
    #pragma unroll
    for (int fi = 0; fi < 4; fi++)
      af[fi] = *reinterpret_cast<const bf16x8*>(&As[wr * 64 + fi * 16 + (lane & 15)][kk * 32 + (lane >> 4) * 8]);
    #pragma unroll
    for (int fj = 0; fj < 4; fj++)
      bfr[fj] = *reinterpret_cast<const bf16x8*>(&Bs[wc * 64 + fj * 16 + (lane & 15)][kk * 32 + (lane >> 4) * 8]);
    #pragma unroll
    for (int fi = 0; fi < 4; fi++)
      #pragma unroll
      for (int fj = 0; fj < 4; fj++)
        acc[fi][fj] = __builtin_amdgcn_mfma_f32_16x16x32_bf16(af[fi], bfr[fj], acc[fi][fj], 0, 0, 0);
  }
  __syncthreads();  // done with As/Bs, reuse as Cs

  #pragma unroll
  for (int fi = 0; fi < 4; fi++)
    #pragma unroll
    for (int fj = 0; fj < 4; fj++)
      #pragma unroll
      for (int j = 0; j < 4; j++)
        Cs[wr * 64 + fi * 16 + ((lane >> 4) << 2) + j][wc * 64 + fj * 16 + (lane & 15)] = acc[fi][fj][j];
  __syncthreads();

  const size_t hbase = ((size_t)head * NSEQ + i0) * NSEQ + j0;
  for (int e = t; e < 128 * 32; e += 256) {
    int row = e >> 5, c4 = (e & 31) * 4;
    size_t off = hbase + (size_t)row * NSEQ + c4;
    float4 hv = *reinterpret_cast<const float4*>(hbuf + off);
    float4 r4 = *reinterpret_cast<const float4*>(&Cs[row][c4]);
    float4 o;
    o.x = 0.05625f * r4.x + 0.55f * hv.x;
    o.y = 0.05625f * r4.y + 0.55f * hv.y;
    o.z = 0.05625f * r4.z + 0.55f * hv.z;
    o.w = 0.05625f * r4.w + 0.55f * hv.w;
    *reinterpret_cast<float4*>(blended + off) = o;
  }
}

// ---------------- row stats: online softmax (m, 1/l) per (g,i) ----------------
__global__ __launch_bounds__(256) void k_stats(const float* __restrict__ blended,
    const float* __restrict__ mixPre, float* __restrict__ mrow, float* __restrict__ rlrow) {
  int i = blockIdx.x;
  int t = threadIdx.x;
  float m[16], l[16];
  #pragma unroll
  for (int g = 0; g < 16; g++) { m[g] = -1e30f; l[g] = 0.f; }

  for (int j = t; j < NSEQ; j += 256) {
    float bl[16];
    #pragma unroll
    for (int hh = 0; hh < 16; hh++)
      bl[hh] = blended[((size_t)hh * NSEQ + i) * NSEQ + j];
    #pragma unroll
    for (int g = 0; g < 16; g++) {
      float d = 0.f;
      #pragma unroll
      for (int hh = 0; hh < 16; hh++) d += bl[hh] * mixPre[hh * 16 + g];
      float mn = fmaxf(m[g], d);
      l[g] = l[g] * __expf(m[g] - mn) + __expf(d - mn);
      m[g] = mn;
    }
  }
  int lane = t & 63, wid = t >> 6;
  #pragma unroll
  for (int g = 0; g < 16; g++) {
    for (int off = 32; off; off >>= 1) {
      float mo = __shfl_xor(m[g], off);
      float lo = __shfl_xor(l[g], off);
      float mn = fmaxf(m[g], mo);
      l[g] = l[g] * __expf(m[g] - mn) + lo * __expf(mo - mn);
      m[g] = mn;
    }
  }
  __shared__ float sm[4][16], sl[4][16];
  if (lane == 0) {
    #pragma unroll
    for (int g = 0; g < 16; g++) { sm[wid][g] = m[g]; sl[wid][g] = l[g]; }
  }
  __syncthreads();
  if (t < 16) {
    int g = t;
    float M = sm[0][g], L = sl[0][g];
    for (int w = 1; w < 4; w++) {
      float mo = sm[w][g], lo = sl[w][g];
      float mn = fmaxf(M, mo);
      L = L * __expf(M - mn) + lo * __expf(mo - mn);
      M = mn;
    }
    mrow[g * NSEQ + i] = M;
    rlrow[g * NSEQ + i] = 1.0f / L;
  }
}

// ---------------- attn materialize: exp/normalize + mix_post -> bf16 ----------------
__global__ __launch_bounds__(256) void k_attn(const float* __restrict__ blended,
    const float* __restrict__ mixPre, const float* __restrict__ mixPost,
    const float* __restrict__ mrow, const float* __restrict__ rlrow,
    unsigned short* __restrict__ attn) {
  int j0 = blockIdx.x * 64, i0 = blockIdx.y * 32;
  int t = threadIdx.x;
  int jj = t & 63, iw = t >> 6;
  int j = j0 + jj;
  for (int ip = 0; ip < 8; ip++) {
    int i = i0 + iw * 8 + ip;
    float bl[16];
    #pragma unroll
    for (int hh = 0; hh < 16; hh++)
      bl[hh] = blended[((size_t)hh * NSEQ + i) * NSEQ + j];
    float a[16];
    #pragma unroll
    for (int g = 0; g < 16; g++) {
      float d = 0.f;
      #pragma unroll
      for (int hh = 0; hh < 16; hh++) d += bl[hh] * mixPre[hh * 16 + g];
      a[g] = __expf(d - mrow[g * NSEQ + i]) * rlrow[g * NSEQ + i];
    }
    #pragma unroll
    for (int g = 0; g < 16; g++) {
      float o = 0.f;
      #pragma unroll
      for (int hh = 0; hh < 16; hh++) o += a[hh] * mixPost[hh * 16 + g];
      attn[((size_t)g * NSEQ + i) * NSEQ + j] = f2bfu(o);
    }
  }
}

// ---------------- PV: out_inner[g] = attn[g] @ v[g] (vT rows: [d][j]) ----------------
__global__ __launch_bounds__(256) void k_pv(const unsigned short* __restrict__ attn,
    const unsigned short* __restrict__ vT, unsigned short* __restrict__ oib) {
  int g = blockIdx.y, i0 = blockIdx.x * 128;
  __shared__ unsigned short As[128][72];
  __shared__ unsigned short Bs[64][72];
  const unsigned short* Ag = attn + (size_t)g * NSEQ * NSEQ;
  const unsigned short* Bg = vT + (size_t)g * 64 * NSEQ;
  int t = threadIdx.x, lane = t & 63, wid = t >> 6;
  f32x4 acc[2][4];
  #pragma unroll
  for (int a = 0; a < 2; a++)
    #pragma unroll
    for (int b = 0; b < 4; b++)
      #pragma unroll
      for (int e = 0; e < 4; e++) acc[a][b][e] = 0.f;

  const int arow = t >> 1, aoff = (t & 1) * 32;
  const int brow = t >> 2, boff = (t & 3) * 16;
  for (int k0 = 0; k0 < NSEQ; k0 += 64) {
    __syncthreads();
    {
      const int4* sa = reinterpret_cast<const int4*>(Ag + (size_t)(i0 + arow) * NSEQ + k0 + aoff);
      int4 a0 = sa[0], a1 = sa[1], a2 = sa[2], a3 = sa[3];
      const int4* sb = reinterpret_cast<const int4*>(Bg + (size_t)brow * NSEQ + k0 + boff);
      int4 b0 = sb[0], b1 = sb[1];
      *reinterpret_cast<int4*>(&As[arow][aoff])      = a0;
      *reinterpret_cast<int4*>(&As[arow][aoff + 8])  = a1;
      *reinterpret_cast<int4*>(&As[arow][aoff + 16]) = a2;
      *reinterpret_cast<int4*>(&As[arow][aoff + 24]) = a3;
      *reinterpret_cast<int4*>(&Bs[brow][boff])      = b0;
      *reinterpret_cast<int4*>(&Bs[brow][boff + 8])  = b1;
    }
    __syncthreads();
    #pragma unroll
    for (int kk = 0; kk < 2; kk++) {
      bf16x8 af[2], bfr[4];
      #pragma unroll
      for (int fi = 0; fi < 2; fi++)
        af[fi] = *reinterpret_cast<const bf16x8*>(&As[wid * 32 + fi * 16 + (lane & 15)][kk * 32 + (lane >> 4) * 8]);
      #pragma unroll
      for (int fj = 0; fj < 4; fj++)
        bfr[fj] = *reinterpret_cast<const bf16x8*>(&Bs[fj * 16 + (lane & 15)][kk * 32 + (lane >> 4) * 8]);
      #pragma unroll
      for (int fi = 0; fi < 2; fi++)
        #pragma unroll
        for (int fj = 0; fj < 4; fj++)
          acc[fi][fj] = __builtin_amdgcn_mfma_f32_16x16x32_bf16(af[fi], bfr[fj], acc[fi][fj], 0, 0, 0);
    }
  }
  #pragma unroll
  for (int fi = 0; fi < 2; fi++)
    #pragma unroll
    for (int fj = 0; fj < 4; fj++) {
      int rowb = i0 + wid * 32 + fi * 16 + ((lane >> 4) << 2);
      int col = g * 64 + fj * 16 + (lane & 15);
      #pragma unroll
      for (int j = 0; j < 4; j++)
        oib[(size_t)(rowb + j) * 1024 + col] = f2bfu(acc[fi][fj][j]);
    }
}

// ---------------- fused attn+PV (low-ws fallback): no attn buffer ----------------
// Per block: i-tile of 16 rows, all 16 g. 4 waves, wave w owns g in [4w, 4w+4).
// Iterate 32 j-tiles of 64: softmax+post-mix -> swizzled LDS bf16 -> MFMA vs vT (L2-resident).
__global__ __launch_bounds__(256) void k_attnpv(const float* __restrict__ blended,
    const float* __restrict__ mixPre, const float* __restrict__ mixPost,
    const float* __restrict__ mrow, const float* __restrict__ rlrow,
    const unsigned short* __restrict__ vT, unsigned short* __restrict__ oib) {
  __shared__ unsigned short aP[16 * 16 * 64];   // [g][i(16)][j(64)] bf16, XOR-swizzled
  __shared__ float mrs[16][16], rls[16][16];    // [g][i]
  int i0 = blockIdx.x * 16;
  int t = threadIdx.x, lane = t & 63, wid = t >> 6;

  for (int v2 = t; v2 < 512; v2 += 256) {
    int g = (v2 & 255) >> 4, ii = v2 & 15;
    if (v2 < 256) mrs[g][ii] = mrow[g * NSEQ + i0 + ii];
    else          rls[g][ii] = rlrow[g * NSEQ + i0 + ii];
  }
  __syncthreads();

  f32x4 acc[4][4];
  #pragma unroll
  for (int a = 0; a < 4; a++)
    #pragma unroll
    for (int b = 0; b < 4; b++)
      #pragma unroll
      for (int e = 0; e < 4; e++) acc[a][b][e] = 0.f;

  for (int jt = 0; jt < 32; ++jt) {
    int j0 = jt * 64;
    // ---- Phase A: 1024 (i,j) pairs over 256 threads ----
    #pragma unroll
    for (int k = 0; k < 4; ++k) {
      int p = t + k * 256;
      int i = p >> 6, j = p & 63;
      float bl[16];
      #pragma unroll
      for (int hh = 0; hh < 16; hh++)
        bl[hh] = blended[((size_t)hh * NSEQ + i0 + i) * NSEQ + j0 + j];
      float aw[16];
      #pragma unroll
      for (int g = 0; g < 16; g++) {
        float d = 0.f;
        #pragma unroll
        for (int hh = 0; hh < 16; hh++) d += bl[hh] * mixPre[hh * 16 + g];
        aw[g] = __expf(d - mrs[g][i]) * rls[g][i];
      }
      #pragma unroll
      for (int g = 0; g < 16; g++) {
        float o = 0.f;
        #pragma unroll
        for (int hh = 0; hh < 16; hh++) o += aw[hh] * mixPost[hh * 16 + g];
        int byt = (((g * 16 + i) * 64 + j) * 2) ^ ((i & 7) << 4);
        *reinterpret_cast<unsigned short*>(reinterpret_cast<char*>(aP) + byt) = f2bfu(o);
      }
    }
    __syncthreads();
    // ---- Phase B: per wave, 4 g; A from LDS (swizzled), B from global vT ----
    #pragma unroll
    for (int g4 = 0; g4 < 4; ++g4) {
      int g = wid * 4 + g4;
      #pragma unroll
      for (int kk = 0; kk < 2; kk++) {
        int arow = g * 16 + (lane & 15);
        int abyt = ((arow * 64 + kk * 32 + (lane >> 4) * 8) * 2) ^ (((lane & 15) & 7) << 4);
        bf16x8 aA = *reinterpret_cast<const bf16x8*>(reinterpret_cast<const char*>(aP) + abyt);
        #pragma unroll
        for (int df = 0; df < 4; df++) {
          bf16x8 bB = *reinterpret_cast<const bf16x8*>(
              vT + (size_t)(g * 64 + df * 16 + (lane & 15)) * NSEQ + j0 + kk * 32 + (lane >> 4) * 8);
          acc[g4][df] = __builtin_amdgcn_mfma_f32_16x16x32_bf16(aA, bB, acc[g4][df], 0, 0, 0);
        }
      }
    }
    __syncthreads();
  }
  #pragma unroll
  for (int g4 = 0; g4 < 4; ++g4) {
    #pragma unroll
    for (int df = 0; df < 4; df++) {
      int col = (wid * 4 + g4) * 64 + df * 16 + (lane & 15);
      int rowb = i0 + ((lane >> 4) << 2);
      #pragma unroll
      for (int e = 0; e < 4; e++)
        oib[(size_t)(rowb + e) * 1024 + col] = f2bfu(acc[g4][df][e]);
    }
  }
}

extern "C" void kernel_launch(void* const* d_in, const int* in_sizes, int n_in,
                              void* d_out, int out_size, void* d_ws, size_t ws_size,
                              hipStream_t stream) {
  const float* x      = (const float*)d_in[0];
  const float* hbuf   = (const float*)d_in[1];
  const float* ln_g   = (const float*)d_in[2];
  const float* ln_b   = (const float*)d_in[3];
  const float* Wq     = (const float*)d_in[4];
  const float* Wkv    = (const float*)d_in[5];
  const float* mixPre = (const float*)d_in[6];
  const float* mixPost= (const float*)d_in[7];
  const float* Wout   = (const float*)d_in[8];
  const float* bout   = (const float*)d_in[9];

  float* outp    = (float*)d_out;
  float* blended = outp + (size_t)NSEQ * DIMM;   // output 1 region

  char* ws = (char*)d_ws;
  unsigned short* xnb = (unsigned short*)ws;                       // 2048x1024 bf16 (4MB)
  unsigned short* Wt  = xnb + (size_t)NSEQ * DIMM;                 // 3072x1024 bf16 (6MB)
  unsigned short* WoT = Wt + (size_t)3072 * 1024;                  // 1024x1024 bf16 (2MB)
  unsigned short* qb  = WoT + (size_t)1024 * 1024;                 // 2048x1024 bf16 (4MB)
  unsigned short* kb  = qb + (size_t)NSEQ * DIMM;                  // 2048x1024 bf16 (4MB)
  unsigned short* vT  = kb + (size_t)NSEQ * DIMM;                  // 1024x2048 bf16 (4MB)
  unsigned short* oib = vT + (size_t)1024 * NSEQ;                  // 2048x1024 bf16 (4MB)
  float* mrow  = (float*)(oib + (size_t)NSEQ * DIMM);              // 16x2048 f32
  float* rlrow = mrow + 16 * NSEQ;                                 // 16x2048 f32
  unsigned short* attn = (unsigned short*)(rlrow + 16 * NSEQ);     // 16x2048x2048 bf16 (128MB)

  // primary path needs ~156.3MB of ws; fall back to fused attn+PV (no attn buffer) otherwise
  bool bigws = ws_size >= (size_t)157 * 1024 * 1024;

  // 1. weight transposes+casts
  k_tcast<<<dim3(32, 32), 256, 0, stream>>>(Wq,   1024, 0,    Wt,                       1024);
  k_tcast<<<dim3(32, 32), 256, 0, stream>>>(Wkv,  2048, 0,    Wt + (size_t)1024 * 1024, 1024);
  k_tcast<<<dim3(32, 32), 256, 0, stream>>>(Wkv,  2048, 1024, Wt + (size_t)2048 * 1024, 1024);
  k_tcast<<<dim3(32, 32), 256, 0, stream>>>(Wout, 1024, 0,    WoT,                      1024);
  // 2. layernorm
  k_layernorm<<<NSEQ, 256, 0, stream>>>(x, ln_g, ln_b, xnb);
  // 3. QKV projection
  k_gemm<0><<<dim3(24, 16), 256, 0, stream>>>(xnb, Wt, 1024, qb, kb, vT, nullptr, nullptr);
  // 4. per-head QK^T + blend
  k_blend<<<dim3(16, 16, 16), 256, 0, stream>>>(qb, kb, hbuf, blended);
  // 5. softmax row stats
  k_stats<<<NSEQ, 256, 0, stream>>>(blended, mixPre, mrow, rlrow);
  if (bigws) {
    // 6. attn materialize (pre-mix, softmax, post-mix)
    k_attn<<<dim3(32, 64), 256, 0, stream>>>(blended, mixPre, mixPost, mrow, rlrow, attn);
    // 7. PV
    k_pv<<<dim3(16, 16), 256, 0, stream>>>(attn, vT, oib);
  } else {
    // 6+7 fused, no attn buffer
    k_attnpv<<<dim3(128), 256, 0, stream>>>(blended, mixPre, mixPost, mrow, rlrow, vT, oib);
  }
  // 8. output projection + bias
  k_gemm<1><<<dim3(8, 16), 256, 0, stream>>>(oib, WoT, 1024, nullptr, nullptr, nullptr, outp, bout);
}